// Round 1
// baseline (1214.995 us; speedup 1.0000x reference)
//
#include <hip/hip_runtime.h>
#include <math.h>

// Problem constants (fixed by the reference).
#define DD 2001      // feature dim
#define CC 20        // classes
#define NN 100000    // rows
#define REGC 0.001f

__device__ __forceinline__ float4 ld4(const float* p) {
  return *reinterpret_cast<const float4*>(p);
}

// weight(d, c) = W[d*STRD + c*STRC]
// Transposed layout (preferred): STRD=CC, STRC=1  -> contiguous scalar loads per d-chunk
// Direct layout (fallback):      STRD=1,  STRC=DD
template <int STRD, int STRC>
__global__ __launch_bounds__(64) void loss_main(
    const float* __restrict__ X,
    const float* __restrict__ Wp,
    const int* __restrict__ Y,
    float* __restrict__ out) {
  const float* W = (const float*)__builtin_assume_aligned(Wp, 64);
  const int lane = threadIdx.x;            // 64-thread block == one wave
  const int row0 = blockIdx.x * 64 + lane; // one row per lane
  const bool valid = row0 < NN;
  const int row = valid ? row0 : (NN - 1); // clamp; masked out of the sum later
  const float* xr = X + (size_t)row * DD;

  float acc[CC];
#pragma unroll
  for (int c = 0; c < CC; ++c) acc[c] = 0.f;

  // 125 chunks of 16 floats cover d=0..1999; d=2000 handled in tail.
  float4 c0 = ld4(xr), c1 = ld4(xr + 4), c2 = ld4(xr + 8), c3 = ld4(xr + 12);
#pragma unroll 1
  for (int k = 0; k < 125; ++k) {
    float4 n0 = {0, 0, 0, 0}, n1 = {0, 0, 0, 0}, n2 = {0, 0, 0, 0}, n3 = {0, 0, 0, 0};
    if (k < 124) {  // prefetch next chunk: 4 outstanding dwordx4 during compute
      const float* p = xr + (k + 1) * 16;
      n0 = ld4(p); n1 = ld4(p + 4); n2 = ld4(p + 8); n3 = ld4(p + 12);
    }
    const int dbase = k * 16;
#pragma unroll
    for (int j = 0; j < 4; ++j) {
      const float4 x = (j == 0) ? c0 : (j == 1) ? c1 : (j == 2) ? c2 : c3;
      const int d0 = dbase + j * 4;
#pragma unroll
      for (int c = 0; c < CC; ++c) {
        float a = acc[c];
        a = fmaf(x.x, W[(d0 + 0) * STRD + c * STRC], a);
        a = fmaf(x.y, W[(d0 + 1) * STRD + c * STRC], a);
        a = fmaf(x.z, W[(d0 + 2) * STRD + c * STRC], a);
        a = fmaf(x.w, W[(d0 + 3) * STRD + c * STRC], a);
        acc[c] = a;
      }
    }
    c0 = n0; c1 = n1; c2 = n2; c3 = n3;
  }
  // tail element d = 2000
  {
    const float x = xr[DD - 1];
#pragma unroll
    for (int c = 0; c < CC; ++c)
      acc[c] = fmaf(x, W[(DD - 1) * STRD + c * STRC], acc[c]);
  }

  // per-row loss: picked + logsumexp(-scores)
  float mx = -3.402823466e38f;
#pragma unroll
  for (int c = 0; c < CC; ++c) mx = fmaxf(mx, -acc[c]);
  float s = 0.f;
#pragma unroll
  for (int c = 0; c < CC; ++c) s += __expf(-acc[c] - mx);
  const int y = valid ? Y[row] : 0;
  float picked = 0.f;
#pragma unroll
  for (int c = 0; c < CC; ++c) picked = (c == y) ? acc[c] : picked;  // no dynamic reg index -> no scratch
  float li = picked + mx + __logf(s);
  li = valid ? li : 0.f;

  // wave (==block) butterfly reduction over 64 lanes
#pragma unroll
  for (int off = 32; off > 0; off >>= 1) li += __shfl_xor(li, off, 64);
  if (lane == 0) atomicAdd(out, li * (1.0f / NN));
}

// Runs FIRST on the stream: out[0] = REG * ||init_weights||_F  (plain store, no memset needed)
__global__ void reg_kernel(const float* __restrict__ IW, float* __restrict__ out) {
  __shared__ float red[256];
  float s = 0.f;
  for (int i = threadIdx.x; i < CC * DD; i += 256) {
    float v = IW[i];
    s += v * v;
  }
  red[threadIdx.x] = s;
  __syncthreads();
  for (int w = 128; w > 0; w >>= 1) {
    if (threadIdx.x < w) red[threadIdx.x] += red[threadIdx.x + w];
    __syncthreads();
  }
  if (threadIdx.x == 0) out[0] = REGC * sqrtf(red[0]);
}

__global__ void transpose_w(const float* __restrict__ W, float* __restrict__ Wt) {
  int i = blockIdx.x * 256 + threadIdx.x;
  if (i < CC * DD) {
    int c = i / DD;
    int d = i - c * DD;
    Wt[d * CC + c] = W[i];
  }
}

extern "C" void kernel_launch(void* const* d_in, const int* in_sizes, int n_in,
                              void* d_out, int out_size, void* d_ws, size_t ws_size,
                              hipStream_t stream) {
  const float* W  = (const float*)d_in[0];   // weights [C, D]
  const float* X  = (const float*)d_in[1];   // X [N, D]
  const int*   Y  = (const int*)d_in[2];     // Y [N]
  const float* IW = (const float*)d_in[3];   // init_weights [C, D]
  float* out = (float*)d_out;

  // 1) constant reg term (overwrites poisoned d_out)
  reg_kernel<<<1, 256, 0, stream>>>(IW, out);

  const int nblocks = (NN + 63) / 64;  // 1563 single-wave blocks, ~6.1/CU, all co-resident
  if (ws_size >= (size_t)(CC * DD) * sizeof(float)) {
    // 2) transpose weights -> Wt[d][c] in workspace (contiguous uniform loads per d-chunk)
    float* Wt = (float*)d_ws;
    transpose_w<<<(CC * DD + 255) / 256, 256, 0, stream>>>(W, Wt);
    // 3) main streaming kernel
    loss_main<CC, 1><<<nblocks, 64, 0, stream>>>(X, Wt, Y, out);
  } else {
    loss_main<1, DD><<<nblocks, 64, 0, stream>>>(X, W, Y, out);
  }
}